// Round 1
// baseline (1241.041 us; speedup 1.0000x reference)
//
#include <hip/hip_runtime.h>

#define N_NODES 100000
#define N_EDGES 640000
#define FEATS   128

// ---------------------------------------------------------------------------
// Phase 1: scatter-add  h[dst[e], :] += feature[src[e], :]
// 32 threads per edge, each thread handles one float4 (4 feats).
// ---------------------------------------------------------------------------
__global__ __launch_bounds__(256) void scatter_kernel(
    const float* __restrict__ feature,
    const int*   __restrict__ edge,   // [2*E] flat: [0..E) = src, [E..2E) = dst
    float*       __restrict__ h) {
  int t    = blockIdx.x * 256 + threadIdx.x;
  int e    = t >> 5;            // edge id
  int lane = t & 31;            // float4 slot within the 128-feat row
  if (e >= N_EDGES) return;
  int s = edge[e];
  int d = edge[N_EDGES + e];
  float4 v = ((const float4*)(feature + (size_t)s * FEATS))[lane];
  float* hp = h + (size_t)d * FEATS + lane * 4;
  atomicAdd(hp + 0, v.x);
  atomicAdd(hp + 1, v.y);
  atomicAdd(hp + 2, v.z);
  atomicAdd(hp + 3, v.w);
}

// ---------------------------------------------------------------------------
// Phase 2: out = h @ W + b   (in-place: h lives in d_out)
// Block: 256 threads, 32 rows. W (64 KB) staged in LDS.
// Thread tile: 4 rows x 4 cols; float4 over k for h, float4 over cols for W.
// In-place safe: each row is read only by the thread that writes it, and the
// write happens after that thread's whole k-loop.
// ---------------------------------------------------------------------------
__global__ __launch_bounds__(256) void gemm_kernel(
    const float* __restrict__ hbuf,   // [N,128]  (== out)
    const float* __restrict__ W,      // [128,128] row-major [k][col]
    const float* __restrict__ bias,   // [128]
    float*       __restrict__ out) {
  __shared__ float Ws[FEATS * FEATS];   // exactly 64 KB

  {
    const float4* srcp = (const float4*)W;
    float4*       dstp = (float4*)Ws;
    #pragma unroll
    for (int i = 0; i < (FEATS * FEATS / 4) / 256; ++i)
      dstp[threadIdx.x + i * 256] = srcp[threadIdx.x + i * 256];
  }
  __syncthreads();

  const int rt   = threadIdx.x >> 5;        // 0..7  (row group)
  const int ct   = threadIdx.x & 31;        // 0..31 (col group)
  const int row0 = blockIdx.x * 32 + rt * 4;
  const int col0 = ct * 4;

  float acc[4][4];
  #pragma unroll
  for (int r = 0; r < 4; ++r)
    #pragma unroll
    for (int c = 0; c < 4; ++c) acc[r][c] = 0.f;

  const float* hrow0 = hbuf + (size_t)row0 * FEATS;

  for (int k = 0; k < FEATS; k += 4) {
    float4 hv[4];
    #pragma unroll
    for (int r = 0; r < 4; ++r)
      hv[r] = *(const float4*)(hrow0 + r * FEATS + k);
    #pragma unroll
    for (int ki = 0; ki < 4; ++ki) {
      float4 wv = *(const float4*)(Ws + (k + ki) * FEATS + col0);
      #pragma unroll
      for (int r = 0; r < 4; ++r) {
        float hk = ((const float*)&hv[r])[ki];
        acc[r][0] += hk * wv.x;
        acc[r][1] += hk * wv.y;
        acc[r][2] += hk * wv.z;
        acc[r][3] += hk * wv.w;
      }
    }
  }

  float4 bv = *(const float4*)(bias + col0);
  #pragma unroll
  for (int r = 0; r < 4; ++r) {
    float4 o;
    o.x = acc[r][0] + bv.x;
    o.y = acc[r][1] + bv.y;
    o.z = acc[r][2] + bv.z;
    o.w = acc[r][3] + bv.w;
    *(float4*)(out + (size_t)(row0 + r) * FEATS + col0) = o;
  }
}

extern "C" void kernel_launch(void* const* d_in, const int* in_sizes, int n_in,
                              void* d_out, int out_size, void* d_ws, size_t ws_size,
                              hipStream_t stream) {
  const float* feature = (const float*)d_in[0];
  const int*   edge    = (const int*)d_in[1];
  const float* W       = (const float*)d_in[2];
  const float* bias    = (const float*)d_in[3];
  float*       out     = (float*)d_out;

  // h = 0 (h lives in d_out; harness poisons it with 0xAA)
  hipMemsetAsync(d_out, 0, (size_t)N_NODES * FEATS * sizeof(float), stream);

  // h[dst] += feature[src]
  scatter_kernel<<<(N_EDGES * 32) / 256, 256, 0, stream>>>(feature, edge, out);

  // out = h @ W + b   (in-place), 100000/32 = 3125 blocks exactly
  gemm_kernel<<<N_NODES / 32, 256, 0, stream>>>(out, W, bias, out);
}

// Round 2
// 281.460 us; speedup vs baseline: 4.4093x; 4.4093x over previous
//
#include <hip/hip_runtime.h>

#define N_NODES 100000
#define N_EDGES 640000
#define FEATS   128

// ---------------- CSR build: counting sort of edges by dst ----------------

__global__ __launch_bounds__(256) void hist_kernel(
    const int* __restrict__ edge, int* __restrict__ cnt) {
  int e = blockIdx.x * 256 + threadIdx.x;
  if (e < N_EDGES) atomicAdd(&cnt[edge[N_EDGES + e]], 1);
}

// per-block exclusive scan of cnt -> off, block totals -> bsum
__global__ __launch_bounds__(256) void scan_block(
    const int* __restrict__ cnt, int* __restrict__ off,
    int* __restrict__ bsum, int n) {
  __shared__ int tmp[256];
  int gid = blockIdx.x * 256 + threadIdx.x;
  int v = (gid < n) ? cnt[gid] : 0;
  tmp[threadIdx.x] = v;
  __syncthreads();
  #pragma unroll
  for (int ofs = 1; ofs < 256; ofs <<= 1) {
    int t = (threadIdx.x >= ofs) ? tmp[threadIdx.x - ofs] : 0;
    __syncthreads();
    tmp[threadIdx.x] += t;
    __syncthreads();
  }
  if (gid < n) off[gid] = tmp[threadIdx.x] - v;  // exclusive
  if (threadIdx.x == 255) bsum[blockIdx.x] = tmp[255];
}

// single-block exclusive scan of the 391 block sums (nb <= 512)
__global__ __launch_bounds__(512) void scan_sums(int* __restrict__ bsum, int nb) {
  __shared__ int tmp[512];
  int v = (threadIdx.x < nb) ? bsum[threadIdx.x] : 0;
  tmp[threadIdx.x] = v;
  __syncthreads();
  #pragma unroll
  for (int ofs = 1; ofs < 512; ofs <<= 1) {
    int t = (threadIdx.x >= ofs) ? tmp[threadIdx.x - ofs] : 0;
    __syncthreads();
    tmp[threadIdx.x] += t;
    __syncthreads();
  }
  if (threadIdx.x < nb) bsum[threadIdx.x] = tmp[threadIdx.x] - v;  // exclusive
}

__global__ __launch_bounds__(256) void add_offsets(
    int* __restrict__ off, int* __restrict__ cur,
    const int* __restrict__ bsum, int n) {
  int gid = blockIdx.x * 256 + threadIdx.x;
  if (gid < n) {
    int o = off[gid] + bsum[blockIdx.x];
    off[gid] = o;
    cur[gid] = o;
  }
}

__global__ __launch_bounds__(256) void fill_csr(
    const int* __restrict__ edge, int* __restrict__ cur,
    int* __restrict__ csr) {
  int e = blockIdx.x * 256 + threadIdx.x;
  if (e < N_EDGES) {
    int d = edge[N_EDGES + e];
    int p = atomicAdd(&cur[d], 1);
    csr[p] = edge[e];  // src
  }
}

// ---------------- Aggregation: one wave per node, no atomics ----------------

__global__ __launch_bounds__(256) void aggregate_kernel(
    const float* __restrict__ feature,
    const int* __restrict__ off, const int* __restrict__ cnt,
    const int* __restrict__ csr, float* __restrict__ h) {
  int node = (blockIdx.x * 256 + threadIdx.x) >> 6;  // one wave64 per node
  int lane = threadIdx.x & 63;                       // float2 slot (2 feats)
  if (node >= N_NODES) return;
  int start = off[node];
  int deg   = cnt[node];
  float2 acc = make_float2(0.f, 0.f);
  int i = 0;
  for (; i + 1 < deg; i += 2) {  // 2-edge unroll for memory-level parallelism
    int s0 = csr[start + i];
    int s1 = csr[start + i + 1];
    float2 v0 = ((const float2*)(feature + (size_t)s0 * FEATS))[lane];
    float2 v1 = ((const float2*)(feature + (size_t)s1 * FEATS))[lane];
    acc.x += v0.x + v1.x;
    acc.y += v0.y + v1.y;
  }
  if (i < deg) {
    int s = csr[start + i];
    float2 v = ((const float2*)(feature + (size_t)s * FEATS))[lane];
    acc.x += v.x;
    acc.y += v.y;
  }
  ((float2*)(h + (size_t)node * FEATS))[lane] = acc;
}

// ---------------- GEMM: out = h @ W + b (in-place on d_out) ----------------

__global__ __launch_bounds__(256) void gemm_kernel(
    const float* __restrict__ hbuf, const float* __restrict__ W,
    const float* __restrict__ bias, float* __restrict__ out) {
  __shared__ float Ws[FEATS * FEATS];  // 64 KB

  {
    const float4* srcp = (const float4*)W;
    float4*       dstp = (float4*)Ws;
    #pragma unroll
    for (int i = 0; i < (FEATS * FEATS / 4) / 256; ++i)
      dstp[threadIdx.x + i * 256] = srcp[threadIdx.x + i * 256];
  }
  __syncthreads();

  const int rt   = threadIdx.x >> 5;
  const int ct   = threadIdx.x & 31;
  const int row0 = blockIdx.x * 32 + rt * 4;
  const int col0 = ct * 4;

  float acc[4][4];
  #pragma unroll
  for (int r = 0; r < 4; ++r)
    #pragma unroll
    for (int c = 0; c < 4; ++c) acc[r][c] = 0.f;

  const float* hrow0 = hbuf + (size_t)row0 * FEATS;

  for (int k = 0; k < FEATS; k += 4) {
    float4 hv[4];
    #pragma unroll
    for (int r = 0; r < 4; ++r)
      hv[r] = *(const float4*)(hrow0 + r * FEATS + k);
    #pragma unroll
    for (int ki = 0; ki < 4; ++ki) {
      float4 wv = *(const float4*)(Ws + (k + ki) * FEATS + col0);
      #pragma unroll
      for (int r = 0; r < 4; ++r) {
        float hk = ((const float*)&hv[r])[ki];
        acc[r][0] += hk * wv.x;
        acc[r][1] += hk * wv.y;
        acc[r][2] += hk * wv.z;
        acc[r][3] += hk * wv.w;
      }
    }
  }

  float4 bv = *(const float4*)(bias + col0);
  #pragma unroll
  for (int r = 0; r < 4; ++r) {
    float4 o;
    o.x = acc[r][0] + bv.x;
    o.y = acc[r][1] + bv.y;
    o.z = acc[r][2] + bv.z;
    o.w = acc[r][3] + bv.w;
    *(float4*)(out + (size_t)(row0 + r) * FEATS + col0) = o;
  }
}

// ---------------------------------------------------------------------------

extern "C" void kernel_launch(void* const* d_in, const int* in_sizes, int n_in,
                              void* d_out, int out_size, void* d_ws, size_t ws_size,
                              hipStream_t stream) {
  const float* feature = (const float*)d_in[0];
  const int*   edge    = (const int*)d_in[1];
  const float* W       = (const float*)d_in[2];
  const float* bias    = (const float*)d_in[3];
  float*       out     = (float*)d_out;

  // workspace carve-up (all int32), 256B-aligned regions
  char* ws = (char*)d_ws;
  int* cnt  = (int*)(ws);                        // N_NODES
  int* off  = (int*)(ws + 512 * 1024);           // N_NODES
  int* cur  = (int*)(ws + 1024 * 1024);          // N_NODES
  int* bsum = (int*)(ws + 1536 * 1024);          // 512
  int* csr  = (int*)(ws + 1600 * 1024);          // N_EDGES

  const int NB = (N_NODES + 255) / 256;  // 391 scan blocks

  hipMemsetAsync(cnt, 0, N_NODES * sizeof(int), stream);
  hist_kernel<<<(N_EDGES + 255) / 256, 256, 0, stream>>>(edge, cnt);
  scan_block<<<NB, 256, 0, stream>>>(cnt, off, bsum, N_NODES);
  scan_sums<<<1, 512, 0, stream>>>(bsum, NB);
  add_offsets<<<NB, 256, 0, stream>>>(off, cur, bsum, N_NODES);
  fill_csr<<<(N_EDGES + 255) / 256, 256, 0, stream>>>(edge, cur, csr);

  // h = segment_sum(feature[src], dst)  -> writes every row of d_out
  aggregate_kernel<<<(N_NODES * 64 + 255) / 256, 256, 0, stream>>>(
      feature, off, cnt, csr, out);

  // out = h @ W + b (in-place)
  gemm_kernel<<<N_NODES / 32, 256, 0, stream>>>(out, W, bias, out);
}

// Round 3
// 224.581 us; speedup vs baseline: 5.5260x; 1.2533x over previous
//
#include <hip/hip_runtime.h>

#define N_NODES 100000
#define N_EDGES 640000
#define FEATS   128

typedef __attribute__((ext_vector_type(8))) short short8;
typedef __attribute__((ext_vector_type(4))) float f32x4;

static __device__ __forceinline__ unsigned short f2bf(float f) {
  union { float f; unsigned u; } c; c.f = f;
  unsigned u = c.u + 0x7fffu + ((c.u >> 16) & 1u);
  return (unsigned short)(u >> 16);
}
static __device__ __forceinline__ float asf(unsigned u) {
  union { unsigned u; float f; } c; c.u = u;
  return c.f;
}

// ---------------- CSR build: counting sort of edges by dst ----------------

__global__ __launch_bounds__(256) void hist_kernel(
    const int* __restrict__ edge, int* __restrict__ cnt) {
  int e = blockIdx.x * 256 + threadIdx.x;
  if (e < N_EDGES) atomicAdd(&cnt[edge[N_EDGES + e]], 1);
}

__global__ __launch_bounds__(256) void scan_block(
    const int* __restrict__ cnt, int* __restrict__ off,
    int* __restrict__ bsum, int n) {
  __shared__ int tmp[256];
  int gid = blockIdx.x * 256 + threadIdx.x;
  int v = (gid < n) ? cnt[gid] : 0;
  tmp[threadIdx.x] = v;
  __syncthreads();
  #pragma unroll
  for (int ofs = 1; ofs < 256; ofs <<= 1) {
    int t = (threadIdx.x >= ofs) ? tmp[threadIdx.x - ofs] : 0;
    __syncthreads();
    tmp[threadIdx.x] += t;
    __syncthreads();
  }
  if (gid < n) off[gid] = tmp[threadIdx.x] - v;  // exclusive
  if (threadIdx.x == 255) bsum[blockIdx.x] = tmp[255];
}

__global__ __launch_bounds__(512) void scan_sums(int* __restrict__ bsum, int nb) {
  __shared__ int tmp[512];
  int v = (threadIdx.x < nb) ? bsum[threadIdx.x] : 0;
  tmp[threadIdx.x] = v;
  __syncthreads();
  #pragma unroll
  for (int ofs = 1; ofs < 512; ofs <<= 1) {
    int t = (threadIdx.x >= ofs) ? tmp[threadIdx.x - ofs] : 0;
    __syncthreads();
    tmp[threadIdx.x] += t;
    __syncthreads();
  }
  if (threadIdx.x < nb) bsum[threadIdx.x] = tmp[threadIdx.x] - v;
}

__global__ __launch_bounds__(256) void add_offsets(
    int* __restrict__ off, int* __restrict__ cur,
    const int* __restrict__ bsum, int n) {
  int gid = blockIdx.x * 256 + threadIdx.x;
  if (gid < n) {
    int o = off[gid] + bsum[blockIdx.x];
    off[gid] = o;
    cur[gid] = o;
  }
}

__global__ __launch_bounds__(256) void fill_csr(
    const int* __restrict__ edge, int* __restrict__ cur,
    int* __restrict__ csr) {
  int e = blockIdx.x * 256 + threadIdx.x;
  if (e < N_EDGES) {
    int d = edge[N_EDGES + e];
    int p = atomicAdd(&cur[d], 1);
    csr[p] = edge[e];  // src
  }
}

// ---------------- fp32 -> bf16 conversions (one-time per call) -------------

// feature [N,128] fp32 -> bf16, 8 elems/thread
__global__ __launch_bounds__(256) void convert_feat(
    const float* __restrict__ src, unsigned short* __restrict__ dst) {
  size_t g = blockIdx.x * 256 + threadIdx.x;           // 0 .. 1.6M-1
  const float4* s = (const float4*)src + g * 2;
  float4 a = s[0], b = s[1];
  unsigned short o[8] = {f2bf(a.x), f2bf(a.y), f2bf(a.z), f2bf(a.w),
                         f2bf(b.x), f2bf(b.y), f2bf(b.z), f2bf(b.w)};
  *(short8*)(dst + g * 8) = *(const short8*)o;
}

// W [k][n] fp32 -> WT [n][k] bf16
__global__ __launch_bounds__(256) void transpose_w(
    const float* __restrict__ W, unsigned short* __restrict__ WT) {
  int g = blockIdx.x * 256 + threadIdx.x;   // 16384
  int k = g >> 7, n = g & 127;
  WT[n * 128 + k] = f2bf(W[g]);
}

// ---------------- Aggregation: wave per node, bf16 gather ------------------
// lanes 0-31 process even edges, 32-63 odd edges; each half covers the full
// 256B row (8B/lane); halves combined with shfl_xor(32).

__global__ __launch_bounds__(256) void aggregate_kernel(
    const unsigned short* __restrict__ feat,
    const int* __restrict__ off, const int* __restrict__ cnt,
    const int* __restrict__ csr, unsigned short* __restrict__ h) {
  int node = (blockIdx.x * 256 + threadIdx.x) >> 6;
  if (node >= N_NODES) return;
  int lane = threadIdx.x & 63;
  int half = lane >> 5, sub = lane & 31;
  int start = off[node];
  int deg   = cnt[node];

  float4 acc = make_float4(0.f, 0.f, 0.f, 0.f);
  int i = half;
  for (; i + 2 < deg; i += 4) {   // pair (i, i+2) per iteration
    int s0 = csr[start + i];
    int s1 = csr[start + i + 2];
    uint2 p0 = *(const uint2*)(feat + (size_t)s0 * FEATS + sub * 4);
    uint2 p1 = *(const uint2*)(feat + (size_t)s1 * FEATS + sub * 4);
    acc.x += asf(p0.x << 16) + asf(p1.x << 16);
    acc.y += asf(p0.x & 0xffff0000u) + asf(p1.x & 0xffff0000u);
    acc.z += asf(p0.y << 16) + asf(p1.y << 16);
    acc.w += asf(p0.y & 0xffff0000u) + asf(p1.y & 0xffff0000u);
  }
  if (i < deg) {
    int s = csr[start + i];
    uint2 p = *(const uint2*)(feat + (size_t)s * FEATS + sub * 4);
    acc.x += asf(p.x << 16);
    acc.y += asf(p.x & 0xffff0000u);
    acc.z += asf(p.y << 16);
    acc.w += asf(p.y & 0xffff0000u);
  }

  acc.x += __shfl_xor(acc.x, 32);
  acc.y += __shfl_xor(acc.y, 32);
  acc.z += __shfl_xor(acc.z, 32);
  acc.w += __shfl_xor(acc.w, 32);

  if (half == 0) {
    uint2 o;
    o.x = (unsigned)f2bf(acc.x) | ((unsigned)f2bf(acc.y) << 16);
    o.y = (unsigned)f2bf(acc.z) | ((unsigned)f2bf(acc.w) << 16);
    *(uint2*)(h + (size_t)node * FEATS + sub * 4) = o;
  }
}

// ---------------- GEMM: out = h_bf @ W + b via bf16 MFMA -------------------
// Block = 4 waves x 32 rows = 128 rows. WT staged in LDS (stride 136 kills
// bank conflicts: lanes land 8 banks x 2-way = free).

#define LDSK 136

__global__ __launch_bounds__(256) void gemm_mfma(
    const unsigned short* __restrict__ hbf,   // [N_pad,128] bf16
    const unsigned short* __restrict__ WT,    // [n][k] bf16
    const float* __restrict__ bias,
    float* __restrict__ out) {
  __shared__ unsigned short WTs[128 * LDSK];

  #pragma unroll
  for (int i = 0; i < 8; ++i) {
    int c = threadIdx.x + i * 256;   // 0..2047 chunks of 16B
    int n = c >> 4, j = c & 15;
    *(short8*)&WTs[n * LDSK + j * 8] = *(const short8*)(WT + n * 128 + j * 8);
  }
  __syncthreads();

  const int w    = threadIdx.x >> 6;
  const int lane = threadIdx.x & 63;
  const int ln15 = lane & 15;
  const int quad = lane >> 4;
  const int row_base = blockIdx.x * 128 + w * 32;

  f32x4 acc[2][8] = {};

  #pragma unroll
  for (int kb = 0; kb < 4; ++kb) {
    int kofs = kb * 32 + quad * 8;
    short8 a0 = *(const short8*)(hbf + (size_t)(row_base + ln15) * FEATS + kofs);
    short8 a1 = *(const short8*)(hbf + (size_t)(row_base + 16 + ln15) * FEATS + kofs);
    #pragma unroll
    for (int ct = 0; ct < 8; ++ct) {
      short8 b = *(const short8*)&WTs[(ct * 16 + ln15) * LDSK + kofs];
      acc[0][ct] = __builtin_amdgcn_mfma_f32_16x16x32_bf16(a0, b, acc[0][ct], 0, 0, 0);
      acc[1][ct] = __builtin_amdgcn_mfma_f32_16x16x32_bf16(a1, b, acc[1][ct], 0, 0, 0);
    }
  }

  #pragma unroll
  for (int t = 0; t < 2; ++t) {
    #pragma unroll
    for (int ct = 0; ct < 8; ++ct) {
      int col = ct * 16 + ln15;
      float bv = bias[col];
      #pragma unroll
      for (int r = 0; r < 4; ++r) {
        int row = row_base + t * 16 + quad * 4 + r;
        if (row < N_NODES)
          out[(size_t)row * FEATS + col] = acc[t][ct][r] + bv;
      }
    }
  }
}

// ---------------------------------------------------------------------------

extern "C" void kernel_launch(void* const* d_in, const int* in_sizes, int n_in,
                              void* d_out, int out_size, void* d_ws, size_t ws_size,
                              hipStream_t stream) {
  const float* feature = (const float*)d_in[0];
  const int*   edge    = (const int*)d_in[1];
  const float* W       = (const float*)d_in[2];
  const float* bias    = (const float*)d_in[3];
  float*       out     = (float*)d_out;

  char* ws = (char*)d_ws;
  int* cnt  = (int*)(ws);                                   // 400 KB
  int* off  = (int*)(ws + (512  << 10));                    // 400 KB
  int* cur  = (int*)(ws + (1024 << 10));                    // 400 KB
  int* bsum = (int*)(ws + (1536 << 10));                    // 2 KB
  int* csr  = (int*)(ws + (1600 << 10));                    // 2.56 MB
  unsigned short* WT      = (unsigned short*)(ws + (4300  << 10));  // 32 KB
  unsigned short* feat_bf = (unsigned short*)(ws + (4400  << 10));  // 25.6 MB
  unsigned short* h_bf    = (unsigned short*)(ws + (30000 << 10));  // 25.63 MB (padded rows)

  const int NB = (N_NODES + 255) / 256;  // 391

  hipMemsetAsync(cnt, 0, N_NODES * sizeof(int), stream);
  hist_kernel<<<(N_EDGES + 255) / 256, 256, 0, stream>>>(edge, cnt);
  scan_block<<<NB, 256, 0, stream>>>(cnt, off, bsum, N_NODES);
  scan_sums<<<1, 512, 0, stream>>>(bsum, NB);
  add_offsets<<<NB, 256, 0, stream>>>(off, cur, bsum, N_NODES);
  fill_csr<<<(N_EDGES + 255) / 256, 256, 0, stream>>>(edge, cur, csr);

  convert_feat<<<(N_NODES * FEATS / 8) / 256, 256, 0, stream>>>(feature, feat_bf);
  transpose_w<<<64, 256, 0, stream>>>(W, WT);

  aggregate_kernel<<<(N_NODES * 64) / 256, 256, 0, stream>>>(
      feat_bf, off, cnt, csr, h_bf);

  gemm_mfma<<<(N_NODES + 127) / 128, 256, 0, stream>>>(h_bf, WT, bias, out);
}

// Round 4
// 209.432 us; speedup vs baseline: 5.9257x; 1.0723x over previous
//
#include <hip/hip_runtime.h>

#define N_NODES 100000
#define N_EDGES 640000
#define FEATS   128

typedef __attribute__((ext_vector_type(8))) short short8;
typedef __attribute__((ext_vector_type(4))) float f32x4;

static __device__ __forceinline__ unsigned short f2bf(float f) {
  union { float f; unsigned u; } c; c.f = f;
  unsigned u = c.u + 0x7fffu + ((c.u >> 16) & 1u);
  return (unsigned short)(u >> 16);
}
static __device__ __forceinline__ float asf(unsigned u) {
  union { unsigned u; float f; } c; c.u = u;
  return c.f;
}

// ---------------------------------------------------------------------------
// prep: [0,6250) convert feature fp32->bf16 ; [6250,6314) transpose W ;
//       [6314,6412) zero cnt.  Branch is block-uniform (no divergence).
// ---------------------------------------------------------------------------
__global__ __launch_bounds__(256) void prep_kernel(
    const float* __restrict__ feature, const float* __restrict__ W,
    unsigned short* __restrict__ feat_bf, unsigned short* __restrict__ WT,
    int* __restrict__ cnt) {
  int b = blockIdx.x;
  if (b < 6250) {
    size_t g = (size_t)b * 256 + threadIdx.x;          // 1.6M chunks of 8
    const float4* s = (const float4*)feature + g * 2;
    float4 a = s[0], c = s[1];
    unsigned short o[8] = {f2bf(a.x), f2bf(a.y), f2bf(a.z), f2bf(a.w),
                           f2bf(c.x), f2bf(c.y), f2bf(c.z), f2bf(c.w)};
    *(short8*)(feat_bf + g * 8) = *(const short8*)o;
  } else if (b < 6314) {
    int g = (b - 6250) * 256 + threadIdx.x;            // 16384
    int k = g >> 7, n = g & 127;
    WT[n * 128 + k] = f2bf(W[g]);
  } else {
    int idx = (b - 6314) * 256 + threadIdx.x;          // 25000 int4s
    if (idx < N_NODES / 4) ((int4*)cnt)[idx] = make_int4(0, 0, 0, 0);
  }
}

// ---------------- CSR build ----------------

__global__ __launch_bounds__(256) void hist_kernel(
    const int* __restrict__ edge, int* __restrict__ cnt) {
  int e = blockIdx.x * 256 + threadIdx.x;
  if (e < N_EDGES) atomicAdd(&cnt[edge[N_EDGES + e]], 1);
}

__global__ __launch_bounds__(256) void scan_block(
    const int* __restrict__ cnt, int* __restrict__ off,
    int* __restrict__ bsum, int n) {
  __shared__ int tmp[256];
  int gid = blockIdx.x * 256 + threadIdx.x;
  int v = (gid < n) ? cnt[gid] : 0;
  tmp[threadIdx.x] = v;
  __syncthreads();
  #pragma unroll
  for (int ofs = 1; ofs < 256; ofs <<= 1) {
    int t = (threadIdx.x >= ofs) ? tmp[threadIdx.x - ofs] : 0;
    __syncthreads();
    tmp[threadIdx.x] += t;
    __syncthreads();
  }
  if (gid < n) off[gid] = tmp[threadIdx.x] - v;  // exclusive within block
  if (threadIdx.x == 255) bsum[blockIdx.x] = tmp[255];
}

// add block-prefix via inline lookback over bsum (NB=391 values, cheap)
__global__ __launch_bounds__(256) void add_offsets(
    int* __restrict__ off, int* __restrict__ cur,
    const int* __restrict__ bsum, int n) {
  __shared__ int wsum[4];
  int s = 0;
  for (int j = threadIdx.x; j < blockIdx.x; j += 256) s += bsum[j];
  #pragma unroll
  for (int o = 32; o > 0; o >>= 1) s += __shfl_down(s, o);
  if ((threadIdx.x & 63) == 0) wsum[threadIdx.x >> 6] = s;
  __syncthreads();
  int base = wsum[0] + wsum[1] + wsum[2] + wsum[3];
  int gid = blockIdx.x * 256 + threadIdx.x;
  if (gid < n) {
    int o = off[gid] + base;
    off[gid] = o;
    cur[gid] = o;
  }
}

__global__ __launch_bounds__(256) void fill_csr(
    const int* __restrict__ edge, int* __restrict__ cur,
    int* __restrict__ csr) {
  int e = blockIdx.x * 256 + threadIdx.x;
  if (e < N_EDGES) {
    int d = edge[N_EDGES + e];
    int p = atomicAdd(&cur[d], 1);
    csr[p] = edge[e];  // src
  }
}

// ---------------------------------------------------------------------------
// Aggregation: 16 lanes per node, uint4 = full 256B bf16 row per wave-instr
// (4 nodes per wave). Each lane accumulates 8 floats; no shuffles; one
// uint4 store per node-quarter.
// ---------------------------------------------------------------------------
__global__ __launch_bounds__(256) void aggregate_kernel(
    const unsigned short* __restrict__ feat,
    const int* __restrict__ off, const int* __restrict__ cnt,
    const int* __restrict__ csr, unsigned short* __restrict__ h) {
  int g    = blockIdx.x * 256 + threadIdx.x;
  int node = g >> 4;          // 16 threads per node
  int lane = g & 15;          // 16B slot (8 bf16)
  if (node >= N_NODES) return;
  int start = off[node];
  int deg   = cnt[node];

  float a0 = 0.f, a1 = 0.f, a2 = 0.f, a3 = 0.f;
  float a4 = 0.f, a5 = 0.f, a6 = 0.f, a7 = 0.f;

  int i = 0;
  for (; i + 1 < deg; i += 2) {       // 2-edge unroll for MLP
    int s0 = csr[start + i];
    int s1 = csr[start + i + 1];
    uint4 p = *(const uint4*)(feat + (size_t)s0 * FEATS + lane * 8);
    uint4 q = *(const uint4*)(feat + (size_t)s1 * FEATS + lane * 8);
    a0 += asf(p.x << 16) + asf(q.x << 16);
    a1 += asf(p.x & 0xffff0000u) + asf(q.x & 0xffff0000u);
    a2 += asf(p.y << 16) + asf(q.y << 16);
    a3 += asf(p.y & 0xffff0000u) + asf(q.y & 0xffff0000u);
    a4 += asf(p.z << 16) + asf(q.z << 16);
    a5 += asf(p.z & 0xffff0000u) + asf(q.z & 0xffff0000u);
    a6 += asf(p.w << 16) + asf(q.w << 16);
    a7 += asf(p.w & 0xffff0000u) + asf(q.w & 0xffff0000u);
  }
  if (i < deg) {
    int s = csr[start + i];
    uint4 p = *(const uint4*)(feat + (size_t)s * FEATS + lane * 8);
    a0 += asf(p.x << 16);
    a1 += asf(p.x & 0xffff0000u);
    a2 += asf(p.y << 16);
    a3 += asf(p.y & 0xffff0000u);
    a4 += asf(p.z << 16);
    a5 += asf(p.z & 0xffff0000u);
    a6 += asf(p.w << 16);
    a7 += asf(p.w & 0xffff0000u);
  }

  uint4 o;
  o.x = (unsigned)f2bf(a0) | ((unsigned)f2bf(a1) << 16);
  o.y = (unsigned)f2bf(a2) | ((unsigned)f2bf(a3) << 16);
  o.z = (unsigned)f2bf(a4) | ((unsigned)f2bf(a5) << 16);
  o.w = (unsigned)f2bf(a6) | ((unsigned)f2bf(a7) << 16);
  *(uint4*)(h + (size_t)node * FEATS + lane * 8) = o;
}

// ---------------- GEMM: out = h_bf @ W + b via bf16 MFMA -------------------

#define LDSK 136

__global__ __launch_bounds__(256) void gemm_mfma(
    const unsigned short* __restrict__ hbf,
    const unsigned short* __restrict__ WT,    // [n][k] bf16
    const float* __restrict__ bias,
    float* __restrict__ out) {
  __shared__ unsigned short WTs[128 * LDSK];

  #pragma unroll
  for (int i = 0; i < 8; ++i) {
    int c = threadIdx.x + i * 256;
    int n = c >> 4, j = c & 15;
    *(short8*)&WTs[n * LDSK + j * 8] = *(const short8*)(WT + n * 128 + j * 8);
  }
  __syncthreads();

  const int w    = threadIdx.x >> 6;
  const int lane = threadIdx.x & 63;
  const int ln15 = lane & 15;
  const int quad = lane >> 4;
  const int row_base = blockIdx.x * 128 + w * 32;

  f32x4 acc[2][8] = {};

  #pragma unroll
  for (int kb = 0; kb < 4; ++kb) {
    int kofs = kb * 32 + quad * 8;
    short8 a0 = *(const short8*)(hbf + (size_t)(row_base + ln15) * FEATS + kofs);
    short8 a1 = *(const short8*)(hbf + (size_t)(row_base + 16 + ln15) * FEATS + kofs);
    #pragma unroll
    for (int ct = 0; ct < 8; ++ct) {
      short8 b = *(const short8*)&WTs[(ct * 16 + ln15) * LDSK + kofs];
      acc[0][ct] = __builtin_amdgcn_mfma_f32_16x16x32_bf16(a0, b, acc[0][ct], 0, 0, 0);
      acc[1][ct] = __builtin_amdgcn_mfma_f32_16x16x32_bf16(a1, b, acc[1][ct], 0, 0, 0);
    }
  }

  #pragma unroll
  for (int t = 0; t < 2; ++t) {
    #pragma unroll
    for (int ct = 0; ct < 8; ++ct) {
      int col = ct * 16 + ln15;
      float bv = bias[col];
      #pragma unroll
      for (int r = 0; r < 4; ++r) {
        int row = row_base + t * 16 + quad * 4 + r;
        if (row < N_NODES)
          out[(size_t)row * FEATS + col] = acc[t][ct][r] + bv;
      }
    }
  }
}

// ---------------------------------------------------------------------------

extern "C" void kernel_launch(void* const* d_in, const int* in_sizes, int n_in,
                              void* d_out, int out_size, void* d_ws, size_t ws_size,
                              hipStream_t stream) {
  const float* feature = (const float*)d_in[0];
  const int*   edge    = (const int*)d_in[1];
  const float* W       = (const float*)d_in[2];
  const float* bias    = (const float*)d_in[3];
  float*       out     = (float*)d_out;

  char* ws = (char*)d_ws;
  int* cnt  = (int*)(ws);                                   // 400 KB
  int* off  = (int*)(ws + (512  << 10));                    // 400 KB
  int* cur  = (int*)(ws + (1024 << 10));                    // 400 KB
  int* bsum = (int*)(ws + (1536 << 10));                    // 2 KB
  int* csr  = (int*)(ws + (1600 << 10));                    // 2.56 MB
  unsigned short* WT      = (unsigned short*)(ws + (4300  << 10));  // 32 KB
  unsigned short* feat_bf = (unsigned short*)(ws + (4400  << 10));  // 25.6 MB
  unsigned short* h_bf    = (unsigned short*)(ws + (30000 << 10));  // 25.6 MB

  const int NB = (N_NODES + 255) / 256;  // 391

  // zero cnt + feature->bf16 + W transpose, one launch (6250+64+98 blocks)
  prep_kernel<<<6412, 256, 0, stream>>>(feature, W, feat_bf, WT, cnt);

  hist_kernel<<<(N_EDGES + 255) / 256, 256, 0, stream>>>(edge, cnt);
  scan_block<<<NB, 256, 0, stream>>>(cnt, off, bsum, N_NODES);
  add_offsets<<<NB, 256, 0, stream>>>(off, cur, bsum, N_NODES);
  fill_csr<<<(N_EDGES + 255) / 256, 256, 0, stream>>>(edge, cur, csr);

  // h = segment_sum(feature[src], dst), bf16
  aggregate_kernel<<<(N_NODES * 16 + 255) / 256, 256, 0, stream>>>(
      feat_bf, off, cnt, csr, h_bf);

  // out = h @ W + b
  gemm_mfma<<<(N_NODES + 127) / 128, 256, 0, stream>>>(h_bf, WT, bias, out);
}